// Round 3
// baseline (1150.547 us; speedup 1.0000x reference)
//
#include <hip/hip_runtime.h>
#include <hip/hip_fp16.h>

#define N_TOK 65536
#define K_EMB 8192
#define D_DIM 256
#define LIST_CAP 12288
#define CAND_CAP 16384
#define NSLICE 64          // K_EMB / 128
#define KSLICE 128         // k-rows resident in LDS per phase1 block

typedef unsigned short u16;
typedef unsigned int u32;
typedef unsigned long long u64;
typedef _Float16 f16x8 __attribute__((ext_vector_type(8)));
typedef float f32x16 __attribute__((ext_vector_type(16)));

__device__ __forceinline__ u16 f2h(float f) {   // f32 -> f16 bits, RNE
  union { _Float16 h; u16 u; } c; c.h = (_Float16)f; return c.u;
}
__device__ __forceinline__ f16x8 as_f16x8(uint4 v) {
  union { uint4 u; f16x8 h; } c; c.u = v; return c.h;
}
__device__ __forceinline__ void gld_lds16(const u16* g, u16* l) {
  __builtin_amdgcn_global_load_lds((const __attribute__((address_space(1))) void*)g,
                                   (__attribute__((address_space(3))) void*)l,
                                   16, 0, 0);
}

// ---------------------------------------------------------------- prep
// ehh[k][d]=f16(emb*2^19); e2f[k]=fl32(sum e^2, f64); e2h[k]=f16(-e2*2^24).
// Zeroes both atomic counters (fresh every call -> graph-replay safe).
__global__ void vq_prep(const float* __restrict__ emb, u16* __restrict__ ehh,
                        float* __restrict__ e2f, u16* __restrict__ e2h,
                        int* __restrict__ count, int* __restrict__ candcount) {
  if (blockIdx.x == 0 && threadIdx.x == 0) { *count = 0; *candcount = 0; }
  const int w = threadIdx.x >> 6, lane = threadIdx.x & 63;
  const int k = blockIdx.x * 4 + w;
  const float4 v = ((const float4*)(emb + (size_t)k * D_DIM))[lane];
  uint2 p;
  p.x = (u32)f2h(v.x * 524288.0f) | ((u32)f2h(v.y * 524288.0f) << 16);
  p.y = (u32)f2h(v.z * 524288.0f) | ((u32)f2h(v.w * 524288.0f) << 16);
  ((uint2*)(ehh + (size_t)k * D_DIM))[lane] = p;
  double s = (double)v.x * v.x + (double)v.y * v.y +
             (double)v.z * v.z + (double)v.w * v.w;
  #pragma unroll
  for (int off = 32; off > 0; off >>= 1) s += __shfl_down(s, off);
  if (lane == 0) { e2f[k] = (float)s; e2h[k] = f2h(-(float)s * 16777216.0f); }
}

// ---------------------------------------------------------------- zprep
// zhh[n][d] = f16(z*64) (bit-identical to the pack phase1/cand use) and
// z2f[n] = fl32(sum z^2, f64) — one pass over z.
__global__ void vq_zprep(const float* __restrict__ zg, u16* __restrict__ zhh,
                         float* __restrict__ z2f) {
  const int w = threadIdx.x >> 6, lane = threadIdx.x & 63;
  const int n = blockIdx.x * 4 + w;
  const float4 v = ((const float4*)(zg + (size_t)n * D_DIM))[lane];
  uint2 p;
  p.x = (u32)f2h(v.x * 64.0f) | ((u32)f2h(v.y * 64.0f) << 16);
  p.y = (u32)f2h(v.z * 64.0f) | ((u32)f2h(v.w * 64.0f) << 16);
  ((uint2*)(zhh + (size_t)n * D_DIM))[lane] = p;
  double s = (double)v.x * v.x + (double)v.y * v.y +
             (double)v.z * v.z + (double)v.w * v.w;
  #pragma unroll
  for (int off = 32; off > 0; off >>= 1) s += __shfl_down(s, off);
  if (lane == 0) z2f[n] = (float)s;
}

// ---------------------------------------------------------------- phase 1
// k-resident redesign: each block owns a 128-k slice (64 KB f16, loaded into
// LDS ONCE) and streams 16384 z-rows through registers. Main loop has NO
// barriers and NO vmcnt drains — eliminates the 2-phase stage/drain stall
// that capped the old structure at ~32% of the MFMA floor. Per-wave top-2
// over the full slice-k; per-(slice,n) partials written to global (d_out
// scratch) and folded by vq_merge. MFMA order per (n,k-tile) is unchanged
// (c=0..15 ascending, then e2-fold) -> acc bits identical to vq_cand's.
__launch_bounds__(512, 2)
__global__ void vq_phase1(const u16* __restrict__ zhh, const u16* __restrict__ ehh,
                          const u16* __restrict__ e2h,
                          int* __restrict__ pm1, u32* __restrict__ pk,
                          int* __restrict__ pm2) {
  __shared__ u16 lds[32768];       // 128 k x 256 d f16, frag-major

  const int tid  = threadIdx.x;
  const int w    = tid >> 6;       // wave id: n-strip (32 rows) within z-tile
  const int lane = tid & 63;
  const int col  = lane & 31;
  const int h    = lane >> 5;
  const int slice = blockIdx.x & (NSLICE - 1);
  const int chunk = blockIdx.x >> 6;             // 4 n-chunks of 16384 rows
  const int k0    = slice * KSLICE;
  const int nbase = chunk * 16384;

  // stage the k-slice: 64 chunks (1 KB each), 8 per wave; one-time barrier
  #pragma unroll
  for (int i = 0; i < 8; ++i) {
    int pp = w * 8 + i, qs = pp >> 4, cs = pp & 15;
    gld_lds16(ehh + (size_t)(k0 + qs * 32 + col) * D_DIM + cs * 16 + h * 8,
              &lds[qs * 8192 + cs * 512]);
  }

  uint4 bone = {0, 0, 0, 0};
  if (h == 0) bone.x = 0x3C00u;    // f16 1.0 at kk=0 (e2-fold B-fragment)
  uint4 ea[4] = {{0,0,0,0},{0,0,0,0},{0,0,0,0},{0,0,0,0}};
  #pragma unroll
  for (int kt = 0; kt < 4; ++kt)
    if (h == 0) ea[kt].x = (u32)e2h[k0 + kt * 32 + col];

  __syncthreads();                 // slice staged (one-time drain; ok)

  for (int it = 0; it < 64; ++it) {
    const int n0 = nbase + it * 256 + w * 32;
    const uint4* zp = (const uint4*)(zhh + (size_t)(n0 + col) * D_DIM);
    uint4 zres[16];
    #pragma unroll
    for (int c = 0; c < 16; ++c) zres[c] = zp[c * 2 + h];

    f32x16 acc[4] = {};
    #pragma unroll
    for (int c = 0; c < 16; ++c) {
      f16x8 zb = as_f16x8(zres[c]);
      #pragma unroll
      for (int kt = 0; kt < 4; ++kt) {
        f16x8 a = as_f16x8(*(const uint4*)(&lds[kt * 8192 + c * 512 + lane * 8]));
        acc[kt] = __builtin_amdgcn_mfma_f32_32x32x16_f16(a, zb, acc[kt], 0, 0, 0);
      }
    }
    #pragma unroll
    for (int kt = 0; kt < 4; ++kt)
      acc[kt] = __builtin_amdgcn_mfma_f32_32x32x16_f16(as_f16x8(ea[kt]),
                                                       as_f16x8(bone), acc[kt], 0, 0, 0);

    // top-2 scan: key = (acc<<12) + inv(local k-pos); inv in [4,127], distinct
    int m1 = (int)0x80000000, m2 = (int)0x80000000;
    #pragma unroll
    for (int kt = 0; kt < 4; ++kt) {
      const int base_inv = 127 - kt * 32;
      #pragma unroll
      for (int r = 0; r < 16; ++r) {
        int key = ((int)acc[kt][r] << 12) + (base_inv - ((r & 3) + 8 * (r >> 2)));
        m2 = max(m2, min(m1, key));
        m1 = max(m1, key);
      }
    }
    // decode own k, then merge half-wave k-partitions (lanes l, l^32 share n)
    int pos = 127 - (m1 & 4095);
    int k1 = k0 + pos + 4 * h;
    int o1 = __shfl_xor(m1, 32), o2 = __shfl_xor(m2, 32);
    int ok1 = __shfl_xor(k1, 32);
    bool take = (o1 > m1) || (o1 == m1 && ok1 < k1);
    int loser = take ? m1 : o1;
    if (take) { m1 = o1; k1 = ok1; }
    m2 = max(m2, max(o2, loser));

    if (lane < 32) {
      size_t idx = (size_t)slice * N_TOK + (n0 + col);
      pm1[idx] = m1 >> 12;         // unpacked acc int (sign-preserving)
      pk[idx]  = (u32)k1;
      pm2[idx] = m2 >> 12;
    }
  }
}

// ---------------------------------------------------------------- merge
// Fold 64 per-slice (m1,k1,m2) partials per row -> global top-2; then the
// flag/threshold/list logic (identical semantics to the old in-phase1 code).
__global__ void vq_merge(const float* __restrict__ z2f, const int* __restrict__ pm1,
                         const u32* __restrict__ pk, const int* __restrict__ pm2,
                         int* __restrict__ idx1_ws, int* __restrict__ thrbuf,
                         u64* __restrict__ refbuf, int* __restrict__ list,
                         int* __restrict__ count) {
  const int n = blockIdx.x * 256 + threadIdx.x;
  int M1 = (int)0x80000000, K1 = 0x7FFFFFFF, M2 = (int)0x80000000;
  #pragma unroll 8
  for (int s = 0; s < NSLICE; ++s) {
    size_t idx = (size_t)s * N_TOK + n;
    int a = pm1[idx];
    int k = (int)pk[idx];
    int b = pm2[idx];
    bool take = (a > M1) || (a == M1 && k < K1);
    if (take) { M2 = max(M2, M1); M1 = a; K1 = k; M2 = max(M2, b); }
    else      { M2 = max(M2, a); }            // b <= a is covered
  }
  // per-row f32 bin width of the ref's distance (~z2) in 2^-24 units:
  // bin = 2^(exp-126); +0.01 bump covers just-below-power-of-2 rows.
  int e = (int)((__float_as_uint(z2f[n] + 0.01f) >> 23) & 255);
  e = min(max(e, 127), 140);
  int bin = 1 << (e - 126);
  int p = 0;
  if ((M1 - M2) < (bin * 2 + 128)) {
    int pos = atomicAdd(count, 1);
    if (pos < LIST_CAP) {
      list[pos] = n;
      thrbuf[pos] = M1 - (bin + 256);         // candidate-pass threshold
      refbuf[pos] = 0xFFFFFFFFFFFFFFFFULL;
      p = pos + 1;
    }
  }
  idx1_ws[n] = K1 | (p << 13);
}

// ---------------------------------------------------------------- cand
// Re-run the bit-identical quantized GEMM on flagged (compacted) rows only;
// push every k whose acc >= per-row threshold. K split 4-way across blocks.
__launch_bounds__(512, 2)
__global__ void vq_cand(const float* __restrict__ zg, const u16* __restrict__ ehh,
                        const u16* __restrict__ e2h, const int* __restrict__ count,
                        const int* __restrict__ list, const int* __restrict__ thrbuf,
                        u32* __restrict__ candbuf, int* __restrict__ candcount) {
  __shared__ u16 lds[2][32768];       // 2 x 64 KB: 128 k x 256 d f16, frag-major
  int cnt = *count; if (cnt > LIST_CAP) cnt = LIST_CAP;
  const int rt = blockIdx.x >> 2;     // row tile (64 rows)
  const int ks = blockIdx.x & 3;      // k slice (2048 k)
  if (rt * 64 >= cnt) return;
  const int k0 = ks * 2048;
  const int tid = threadIdx.x, w = tid >> 6, lane = tid & 63;
  const int q = w & 3, g = w >> 2;     // q: k-substrip(0..3), g: row-group(0..1)
  const int col = lane & 31, h = lane >> 5;
  const int ct = rt * 64 + g * 32 + col;         // compact-row index
  const bool valid = ct < cnt;
  const int n_tok = valid ? (list[ct] & (N_TOK - 1)) : 0;
  const int thr = valid ? thrbuf[ct] : 0x7FFFFFFF;

  uint4 zres[16];
  {
    const float4* zp = (const float4*)(zg + (size_t)n_tok * D_DIM);
    #pragma unroll
    for (int c = 0; c < 16; ++c) {
      float4 a = zp[c * 4 + h * 2];
      float4 b2 = zp[c * 4 + h * 2 + 1];
      uint4 u;
      u.x = (u32)f2h(a.x * 64.0f) | ((u32)f2h(a.y * 64.0f) << 16);
      u.y = (u32)f2h(a.z * 64.0f) | ((u32)f2h(a.w * 64.0f) << 16);
      u.z = (u32)f2h(b2.x * 64.0f) | ((u32)f2h(b2.y * 64.0f) << 16);
      u.w = (u32)f2h(b2.z * 64.0f) | ((u32)f2h(b2.w * 64.0f) << 16);
      zres[c] = u;
    }
  }
  uint4 bone = {0, 0, 0, 0};
  if (h == 0) bone.x = 0x3C00u;

  // stage tile 0 of this k-slice: 64 chunks (1 KB each), 8 per wave
  #pragma unroll
  for (int i = 0; i < 8; ++i) {
    int p2 = w * 8 + i, qs = p2 >> 4, cs = p2 & 15;
    gld_lds16(ehh + (size_t)(k0 + qs * 32 + col) * D_DIM + cs * 16 + h * 8,
              &lds[0][qs * 8192 + cs * 512]);
  }

  for (int tK = 0; tK < 16; ++tK) {
    const int b = tK & 1;
    __syncthreads();                  // tile tK staged; tile tK-1 readers done
    if (tK + 1 < 16) {
      const int nb = b ^ 1, kb2 = k0 + (tK + 1) * 128;
      #pragma unroll
      for (int i = 0; i < 8; ++i) {
        int p2 = w * 8 + i, qs = p2 >> 4, cs = p2 & 15;
        gld_lds16(ehh + (size_t)(kb2 + qs * 32 + col) * D_DIM + cs * 16 + h * 8,
                  &lds[nb][qs * 8192 + cs * 512]);
      }
    }
    const int kb = k0 + tK * 128 + q * 32;
    uint4 ea = {0, 0, 0, 0};
    if (h == 0) ea.x = (u32)e2h[kb + col];
    const u16* lb = &lds[b][q * 8192];
    f32x16 acc = {};
    #pragma unroll
    for (int c = 0; c < 16; ++c) {    // same order as phase1 -> bit-identical
      f16x8 a = as_f16x8(*(const uint4*)(lb + c * 512 + lane * 8));
      acc = __builtin_amdgcn_mfma_f32_32x32x16_f16(a, as_f16x8(zres[c]), acc, 0, 0, 0);
    }
    acc = __builtin_amdgcn_mfma_f32_32x32x16_f16(as_f16x8(ea), as_f16x8(bone), acc, 0, 0, 0);
    #pragma unroll
    for (int r = 0; r < 16; ++r) {
      if ((int)acc[r] >= thr) {
        int kg = kb + (r & 3) + 8 * (r >> 2) + 4 * h;
        int pos = atomicAdd(candcount, 1);
        if (pos < CAND_CAP) candbuf[pos] = ((u32)ct << 13) | (u32)kg;
      }
    }
  }
}

// ---------------------------------------------------------------- refine2
// Per candidate: val = fl32(fl32(z2+e2) - 2*fl32(dot)) exactly as np-f32 does;
// key = (val_bits<<13)|k, atomicMin -> min val, tie -> lowest k (first-occurrence).
__global__ void vq_refine2(const float* __restrict__ zg, const float* __restrict__ emb,
                           const float* __restrict__ z2f, const float* __restrict__ e2f,
                           const int* __restrict__ list, const int* __restrict__ candcount,
                           const u32* __restrict__ candbuf, u64* __restrict__ refbuf) {
  const int w = threadIdx.x >> 6, lane = threadIdx.x & 63;
  int ccnt = *candcount; if (ccnt > CAND_CAP) ccnt = CAND_CAP;
  for (int i = blockIdx.x * 4 + w; i < ccnt; i += gridDim.x * 4) {
    const u32 rec = candbuf[i];
    const int p = (int)(rec >> 13), k = (int)(rec & 8191u);
    const int n = list[p] & (N_TOK - 1);
    float4 zv = ((const float4*)(zg + (size_t)n * D_DIM))[lane];
    float4 ev = ((const float4*)(emb + (size_t)k * D_DIM))[lane];
    double s = (double)zv.x * ev.x + (double)zv.y * ev.y +
               (double)zv.z * ev.z + (double)zv.w * ev.w;
    #pragma unroll
    for (int off = 32; off > 0; off >>= 1) s += __shfl_down(s, off);
    if (lane == 0) {
      float S = z2f[n] + e2f[k];           // fl32(z2+e2)
      float val = S - 2.0f * (float)s;     // fl32(S - 2*fl32(dot))
      u64 key = ((u64)__float_as_uint(val) << 13) | (u64)k;
      atomicMin((unsigned long long*)(refbuf + p), (unsigned long long)key);
    }
  }
}

// ---------------------------------------------------------------- gather
// f32 outputs: quantized = straight_through = emb[idx]; indices as f32.
__global__ void vq_gather(const float* __restrict__ emb, const int* __restrict__ idx1_ws,
                          const u64* __restrict__ refbuf, float* __restrict__ out) {
  const int w = threadIdx.x >> 6, lane = threadIdx.x & 63;
  const int n = blockIdx.x * 4 + w;
  const int enc = idx1_ws[n];
  int idx = enc & 8191;
  const int p = enc >> 13;
  if (p > 0) {
    u64 rb = refbuf[p - 1];
    if (rb != 0xFFFFFFFFFFFFFFFFULL) idx = (int)(rb & 8191ULL);
  }
  float4 v = ((const float4*)(emb + (size_t)idx * D_DIM))[lane];
  float4* o = (float4*)out;
  o[(size_t)n * 64 + lane] = v;
  o[(size_t)4194304 + (size_t)n * 64 + lane] = v;         // + N*D (float4 units)
  if (lane == 0) out[(size_t)33554432 + n] = (float)idx;  // + 2*N*D (float units)
}

extern "C" void kernel_launch(void* const* d_in, const int* in_sizes, int n_in,
                              void* d_out, int out_size, void* d_ws, size_t ws_size,
                              hipStream_t stream) {
  const float* z   = (const float*)d_in[0];
  const float* emb = (const float*)d_in[1];
  char* ws = (char*)d_ws;
  // Workspace layout (bytes), total 5,029,896 — within the 5.38 MB envelope.
  u16*   ehh       = (u16*)(ws);                  // [0        .. 4194304)
  float* e2f       = (float*)(ws + 4194304);      // [4194304  .. 4227072)
  u16*   e2h       = (u16*)(ws + 4227072);        // [4227072  .. 4243456)
  float* z2f       = (float*)(ws + 4243456);      // [4243456  .. 4505600)
  int*   idx1_ws   = (int*)(ws + 4505600);        // [4505600  .. 4767744)
  u64*   refbuf    = (u64*)(ws + 4767744);        // [4767744  .. 4866048)  12288*8
  int*   list      = (int*)(ws + 4866048);        // [4866048  .. 4915200)  12288*4
  int*   thrbuf    = (int*)(ws + 4915200);        // [4915200  .. 4964352)  12288*4
  u32*   candbuf   = (u32*)(ws + 4964352);        // [4964352  .. 5029888)  16384*4
  int*   count     = (int*)(ws + 5029888);        // [5029888  .. 5029892)
  int*   candcount = (int*)(ws + 5029892);        // [5029892  .. 5029896)

  // Large scratch lives in d_out (128.25 MB): bytes [0, 80 MB) are dead until
  // vq_gather fully overwrites the output at the end of the launch sequence.
  char* ob = (char*)d_out;
  u16*  zhh = (u16*)(ob);                         // [0        .. 33554432)  32 MB
  int*  pm1 = (int*)(ob + 33554432);              // [32 MB    .. 48 MB)   64*65536*4
  u32*  pkb = (u32*)(ob + 50331648);              // [48 MB    .. 64 MB)
  int*  pm2 = (int*)(ob + 67108864);              // [64 MB    .. 80 MB)

  vq_prep   <<<K_EMB / 4, 256, 0, stream>>>(emb, ehh, e2f, e2h, count, candcount);
  vq_zprep  <<<N_TOK / 4, 256, 0, stream>>>(z, zhh, z2f);
  vq_phase1 <<<256, 512, 0, stream>>>(zhh, ehh, e2h, pm1, pkb, pm2);
  vq_merge  <<<N_TOK / 256, 256, 0, stream>>>(z2f, pm1, pkb, pm2, idx1_ws, thrbuf,
                                              refbuf, list, count);
  vq_cand   <<<768, 512, 0, stream>>>(z, ehh, e2h, count, list, thrbuf,
                                      candbuf, candcount);
  vq_refine2<<<512, 256, 0, stream>>>(z, emb, z2f, e2f, list, candcount,
                                      candbuf, refbuf);
  vq_gather <<<N_TOK / 4, 256, 0, stream>>>(emb, idx1_ws, refbuf, (float*)d_out);
}

// Round 4
// 689.282 us; speedup vs baseline: 1.6692x; 1.6692x over previous
//
#include <hip/hip_runtime.h>
#include <hip/hip_fp16.h>

#define N_TOK 65536
#define K_EMB 8192
#define D_DIM 256
#define LIST_CAP 12288
#define CAND_CAP 16384

typedef unsigned short u16;
typedef unsigned int u32;
typedef unsigned long long u64;
typedef _Float16 f16x8 __attribute__((ext_vector_type(8)));
typedef float f32x16 __attribute__((ext_vector_type(16)));

__device__ __forceinline__ u16 f2h(float f) {   // f32 -> f16 bits, RNE
  union { _Float16 h; u16 u; } c; c.h = (_Float16)f; return c.u;
}
__device__ __forceinline__ f16x8 as_f16x8(uint4 v) {
  union { uint4 u; f16x8 h; } c; c.u = v; return c.h;
}
__device__ __forceinline__ void gld_lds16(const u16* g, u16* l) {
  __builtin_amdgcn_global_load_lds((const __attribute__((address_space(1))) void*)g,
                                   (__attribute__((address_space(3))) void*)l,
                                   16, 0, 0);
}

// ---------------------------------------------------------------- prep
// ehh[k][d]=f16(emb*2^19); e2f[k]=fl32(sum e^2, f64); e2h[k]=f16(-e2*2^24).
// Zeroes both atomic counters (fresh every call -> graph-replay safe).
__global__ void vq_prep(const float* __restrict__ emb, u16* __restrict__ ehh,
                        float* __restrict__ e2f, u16* __restrict__ e2h,
                        int* __restrict__ count, int* __restrict__ candcount) {
  if (blockIdx.x == 0 && threadIdx.x == 0) { *count = 0; *candcount = 0; }
  const int w = threadIdx.x >> 6, lane = threadIdx.x & 63;
  const int k = blockIdx.x * 4 + w;
  const float4 v = ((const float4*)(emb + (size_t)k * D_DIM))[lane];
  uint2 p;
  p.x = (u32)f2h(v.x * 524288.0f) | ((u32)f2h(v.y * 524288.0f) << 16);
  p.y = (u32)f2h(v.z * 524288.0f) | ((u32)f2h(v.w * 524288.0f) << 16);
  ((uint2*)(ehh + (size_t)k * D_DIM))[lane] = p;
  double s = (double)v.x * v.x + (double)v.y * v.y +
             (double)v.z * v.z + (double)v.w * v.w;
  #pragma unroll
  for (int off = 32; off > 0; off >>= 1) s += __shfl_down(s, off);
  if (lane == 0) { e2f[k] = (float)s; e2h[k] = f2h(-(float)s * 16777216.0f); }
}

// ---------------------------------------------------------------- phase 1
// Round-1 dataflow (ehh streamed via L2, z resident in regs) + counted-vmcnt
// deep pipeline (T3/T4): 4 LDS tile buffers, stage(t+3) issued each iter, raw
// s_barrier with vmcnt(8) (never 0 in-loop) so 2 tiles of loads stay in
// flight across every barrier. e2h lives in LDS -> zero global loads in the
// main loop (keeps vmcnt arithmetic exact). Each wave: 2 n-strips x 1
// k-substrip; each A-fragment ds_read feeds 2 MFMAs. z2 row-norm fused into
// the z load (f64, same bits as the old vq_z2). MFMA order per (n,32k) is
// c=0..15 then e2-fold -> bit-identical to vq_cand.
__launch_bounds__(512, 2)
__global__ void vq_phase1(const float* __restrict__ zg, const u16* __restrict__ ehh,
                          const u16* __restrict__ e2h, float* __restrict__ z2f,
                          int* __restrict__ idx1_ws, int* __restrict__ thrbuf,
                          u64* __restrict__ refbuf, int* __restrict__ list,
                          int* __restrict__ count) {
  __shared__ u16 lds[4][16384];    // 4 x 32 KB tile buffers (64 k-rows each)
  __shared__ u16 e2l[8192];        // all of e2h (16 KB)
  __shared__ float z2s[256];       // per-row z2 (fused vq_z2)

  const int tid  = threadIdx.x;
  const int w    = tid >> 6;
  const int lane = tid & 63;
  const int q    = w & 1;          // k-substrip (32 k rows)
  const int g    = w >> 1;         // n-group (64 rows = 2 strips x 32)
  const int col  = lane & 31;
  const int h    = lane >> 5;
  const int n0   = blockIdx.x * 256 + g * 64;

  // e2h -> LDS: 16 chunks of 1 KB, 2 per wave
  #pragma unroll
  for (int i = 0; i < 2; ++i) {
    int pp = w * 2 + i;
    gld_lds16(e2h + pp * 512 + lane * 8, &e2l[pp * 512]);
  }

  // z fragments (f16(z*64), 128 VGPRs) + fused z2 (f64 row norm)
  uint4 zres0[16], zres1[16];
  double zs0 = 0.0, zs1 = 0.0;
#define P1_ZLOAD(ZR, ZS, S) { \
    const float4* zp_ = (const float4*)(zg + (size_t)(n0 + (S) * 32 + col) * D_DIM); \
    _Pragma("unroll") \
    for (int c = 0; c < 16; ++c) { \
      float4 a_ = zp_[c * 4 + h * 2]; \
      float4 b_ = zp_[c * 4 + h * 2 + 1]; \
      ZS += (double)a_.x * a_.x + (double)a_.y * a_.y + \
            (double)a_.z * a_.z + (double)a_.w * a_.w; \
      ZS += (double)b_.x * b_.x + (double)b_.y * b_.y + \
            (double)b_.z * b_.z + (double)b_.w * b_.w; \
      uint4 u_; \
      u_.x = (u32)f2h(a_.x * 64.0f) | ((u32)f2h(a_.y * 64.0f) << 16); \
      u_.y = (u32)f2h(a_.z * 64.0f) | ((u32)f2h(a_.w * 64.0f) << 16); \
      u_.z = (u32)f2h(b_.x * 64.0f) | ((u32)f2h(b_.y * 64.0f) << 16); \
      u_.w = (u32)f2h(b_.z * 64.0f) | ((u32)f2h(b_.w * 64.0f) << 16); \
      ZR[c] = u_; \
    } }
  P1_ZLOAD(zres0, zs0, 0);
  P1_ZLOAD(zres1, zs1, 1);
#undef P1_ZLOAD
  zs0 += __shfl_xor(zs0, 32);      // combine half-rows (h=0 + h=1)
  zs1 += __shfl_xor(zs1, 32);
  if (lane < 32) {                 // q=0,1 waves write identical bits
    z2s[g * 64 + col]      = (float)zs0;  z2f[n0 + col]      = (float)zs0;
    z2s[g * 64 + 32 + col] = (float)zs1;  z2f[n0 + 32 + col] = (float)zs1;
  }

  uint4 bone = {0, 0, 0, 0};
  if (h == 0) bone.x = 0x3C00u;    // f16 1.0 at kk=0 (e2-fold B-fragment)

  int m1[2] = {(int)0x80000000, (int)0x80000000};
  int m2[2] = {(int)0x80000000, (int)0x80000000};

#define P1_STAGE(T) { \
    _Pragma("unroll") \
    for (int i = 0; i < 4; ++i) { \
      int pp_ = w * 4 + i, qs_ = pp_ >> 4, cs_ = pp_ & 15; \
      gld_lds16(ehh + (size_t)((T) * 64 + qs_ * 32 + col) * D_DIM + cs_ * 16 + h * 8, \
                &lds[(T) & 3][qs_ * 8192 + cs_ * 512]); \
    } }
#define P1_STEP(T) { \
    const u16* lb_ = &lds[(T) & 3][q * 8192]; \
    uint4 ea_ = {0, 0, 0, 0}; \
    if (h == 0) ea_.x = (u32)e2l[(T) * 64 + q * 32 + col]; \
    f32x16 a0_ = {}, a1_ = {}; \
    __builtin_amdgcn_s_setprio(1); \
    _Pragma("unroll") \
    for (int c = 0; c < 16; ++c) { \
      f16x8 af_ = as_f16x8(*(const uint4*)(lb_ + c * 512 + lane * 8)); \
      a0_ = __builtin_amdgcn_mfma_f32_32x32x16_f16(af_, as_f16x8(zres0[c]), a0_, 0, 0, 0); \
      a1_ = __builtin_amdgcn_mfma_f32_32x32x16_f16(af_, as_f16x8(zres1[c]), a1_, 0, 0, 0); \
    } \
    a0_ = __builtin_amdgcn_mfma_f32_32x32x16_f16(as_f16x8(ea_), as_f16x8(bone), a0_, 0, 0, 0); \
    a1_ = __builtin_amdgcn_mfma_f32_32x32x16_f16(as_f16x8(ea_), as_f16x8(bone), a1_, 0, 0, 0); \
    __builtin_amdgcn_s_setprio(0); \
    const int bi_ = 4095 - (T) * 32 - q * 16; \
    _Pragma("unroll") \
    for (int r = 0; r < 16; ++r) { \
      int ka_ = ((int)a0_[r] << 12) + (bi_ - r); \
      m2[0] = max(m2[0], min(m1[0], ka_)); \
      m1[0] = max(m1[0], ka_); \
      int kb_ = ((int)a1_[r] << 12) + (bi_ - r); \
      m2[1] = max(m2[1], min(m1[1], kb_)); \
      m1[1] = max(m1[1], kb_); \
    } }

  P1_STAGE(0); P1_STAGE(1); P1_STAGE(2);    // depth-3 prologue
  for (int t = 0; t < 125; ++t) {
    // stage(t) has >=8 younger VMEM ops behind it (stages t+1,t+2) -> vmcnt(8)
    // completes it; barrier then publishes it block-wide. Loads for t+1,t+2
    // remain in flight ACROSS the barrier (T4: never drain to 0 in-loop).
    asm volatile("s_waitcnt vmcnt(8)" ::: "memory");
    asm volatile("s_barrier" ::: "memory");
    P1_STAGE(t + 3);
    P1_STEP(t);
  }
  asm volatile("s_waitcnt vmcnt(8)" ::: "memory");
  asm volatile("s_barrier" ::: "memory");
  P1_STEP(125);
  asm volatile("s_waitcnt vmcnt(4)" ::: "memory");
  asm volatile("s_barrier" ::: "memory");
  P1_STEP(126);
  asm volatile("s_waitcnt vmcnt(0)" ::: "memory");
  asm volatile("s_barrier" ::: "memory");
  P1_STEP(127);
#undef P1_STAGE
#undef P1_STEP

  // decode own k, then merge half-wave k-partitions (lanes l and l^32 share n)
  int k1d[2];
  #pragma unroll
  for (int s = 0; s < 2; ++s) {
    int x = 4095 - (m1[s] & 4095);
    int kt = x >> 5, kq = (x >> 4) & 1, kr = x & 15;
    k1d[s] = kt * 64 + kq * 32 + (kr & 3) + 8 * (kr >> 2) + 4 * h;
    int o1 = __shfl_xor(m1[s], 32), o2 = __shfl_xor(m2[s], 32);
    int ok1 = __shfl_xor(k1d[s], 32);
    bool take = (o1 > m1[s]) || (o1 == m1[s] && ok1 < k1d[s]);
    int loser = take ? m1[s] : o1;
    if (take) { m1[s] = o1; k1d[s] = ok1; }
    m2[s] = max(m2[s], max(o2, loser));
  }

  __syncthreads();                // all tile reads done; alias lds[0]
  int* rm1 = (int*)&lds[0][0];    // [2][256] each
  int* rk1 = (int*)&lds[0][1024];
  int* rm2 = (int*)&lds[0][2048];
  if (lane < 32) {
    #pragma unroll
    for (int s = 0; s < 2; ++s) {
      int nl = q * 256 + g * 64 + s * 32 + col;
      rm1[nl] = m1[s]; rk1[nl] = k1d[s]; rm2[nl] = m2[s];
    }
  }
  __syncthreads();
  if (tid < 256) {
    int a1 = rm1[tid], a2 = rm2[tid], ak = rk1[tid];
    int c1 = rm1[256 + tid], c2 = rm2[256 + tid], ck = rk1[256 + tid];
    bool take = (c1 > a1) || (c1 == a1 && ck < ak);
    int M1 = take ? c1 : a1;
    int K1 = take ? ck : ak;
    int M2 = max(max(a2, c2), take ? a1 : c1);
    int n = blockIdx.x * 256 + tid;
    int M1a = M1 >> 12, M2a = M2 >> 12;
    // per-row f32 bin width of the ref's distance (~z2) in 2^-24 units:
    // bin = 2^(exp-126); +0.01 bump covers just-below-power-of-2 rows.
    int e = (int)((__float_as_uint(z2s[tid] + 0.01f) >> 23) & 255);
    e = min(max(e, 127), 140);
    int bin = 1 << (e - 126);
    int p = 0;
    if ((M1a - M2a) < (bin * 2 + 128)) {
      int pos = atomicAdd(count, 1);
      if (pos < LIST_CAP) {
        list[pos] = n;
        thrbuf[pos] = M1a - (bin + 256);    // candidate-pass threshold
        refbuf[pos] = 0xFFFFFFFFFFFFFFFFULL;
        p = pos + 1;
      }
    }
    idx1_ws[n] = K1 | (p << 13);
  }
}

// ---------------------------------------------------------------- cand
// Re-run the bit-identical quantized GEMM on flagged (compacted) rows only;
// push every k whose acc >= per-row threshold. K split 4-way across blocks.
__launch_bounds__(512, 2)
__global__ void vq_cand(const float* __restrict__ zg, const u16* __restrict__ ehh,
                        const u16* __restrict__ e2h, const int* __restrict__ count,
                        const int* __restrict__ list, const int* __restrict__ thrbuf,
                        u32* __restrict__ candbuf, int* __restrict__ candcount) {
  __shared__ u16 lds[2][32768];       // 2 x 64 KB: 128 k x 256 d f16, frag-major
  int cnt = *count; if (cnt > LIST_CAP) cnt = LIST_CAP;
  const int rt = blockIdx.x >> 2;     // row tile (64 rows)
  const int ks = blockIdx.x & 3;      // k slice (2048 k)
  if (rt * 64 >= cnt) return;
  const int k0 = ks * 2048;
  const int tid = threadIdx.x, w = tid >> 6, lane = tid & 63;
  const int q = w & 3, g = w >> 2;     // q: k-substrip(0..3), g: row-group(0..1)
  const int col = lane & 31, h = lane >> 5;
  const int ct = rt * 64 + g * 32 + col;         // compact-row index
  const bool valid = ct < cnt;
  const int n_tok = valid ? (list[ct] & (N_TOK - 1)) : 0;
  const int thr = valid ? thrbuf[ct] : 0x7FFFFFFF;

  uint4 zres[16];
  {
    const float4* zp = (const float4*)(zg + (size_t)n_tok * D_DIM);
    #pragma unroll
    for (int c = 0; c < 16; ++c) {
      float4 a = zp[c * 4 + h * 2];
      float4 b2 = zp[c * 4 + h * 2 + 1];
      uint4 u;
      u.x = (u32)f2h(a.x * 64.0f) | ((u32)f2h(a.y * 64.0f) << 16);
      u.y = (u32)f2h(a.z * 64.0f) | ((u32)f2h(a.w * 64.0f) << 16);
      u.z = (u32)f2h(b2.x * 64.0f) | ((u32)f2h(b2.y * 64.0f) << 16);
      u.w = (u32)f2h(b2.z * 64.0f) | ((u32)f2h(b2.w * 64.0f) << 16);
      zres[c] = u;
    }
  }
  uint4 bone = {0, 0, 0, 0};
  if (h == 0) bone.x = 0x3C00u;

  // stage tile 0 of this k-slice: 64 chunks (1 KB each), 8 per wave
  #pragma unroll
  for (int i = 0; i < 8; ++i) {
    int p2 = w * 8 + i, qs = p2 >> 4, cs = p2 & 15;
    gld_lds16(ehh + (size_t)(k0 + qs * 32 + col) * D_DIM + cs * 16 + h * 8,
              &lds[0][qs * 8192 + cs * 512]);
  }

  for (int tK = 0; tK < 16; ++tK) {
    const int b = tK & 1;
    __syncthreads();                  // tile tK staged; tile tK-1 readers done
    if (tK + 1 < 16) {
      const int nb = b ^ 1, kb2 = k0 + (tK + 1) * 128;
      #pragma unroll
      for (int i = 0; i < 8; ++i) {
        int p2 = w * 8 + i, qs = p2 >> 4, cs = p2 & 15;
        gld_lds16(ehh + (size_t)(kb2 + qs * 32 + col) * D_DIM + cs * 16 + h * 8,
                  &lds[nb][qs * 8192 + cs * 512]);
      }
    }
    const int kb = k0 + tK * 128 + q * 32;
    uint4 ea = {0, 0, 0, 0};
    if (h == 0) ea.x = (u32)e2h[kb + col];
    const u16* lb = &lds[b][q * 8192];
    f32x16 acc = {};
    #pragma unroll
    for (int c = 0; c < 16; ++c) {    // same order as phase1 -> bit-identical
      f16x8 a = as_f16x8(*(const uint4*)(lb + c * 512 + lane * 8));
      acc = __builtin_amdgcn_mfma_f32_32x32x16_f16(a, as_f16x8(zres[c]), acc, 0, 0, 0);
    }
    acc = __builtin_amdgcn_mfma_f32_32x32x16_f16(as_f16x8(ea), as_f16x8(bone), acc, 0, 0, 0);
    #pragma unroll
    for (int r = 0; r < 16; ++r) {
      if ((int)acc[r] >= thr) {
        int kg = kb + (r & 3) + 8 * (r >> 2) + 4 * h;
        int pos = atomicAdd(candcount, 1);
        if (pos < CAND_CAP) candbuf[pos] = ((u32)ct << 13) | (u32)kg;
      }
    }
  }
}

// ---------------------------------------------------------------- refine2
// Per candidate: val = fl32(fl32(z2+e2) - 2*fl32(dot)) exactly as np-f32 does;
// key = (val_bits<<13)|k, atomicMin -> min val, tie -> lowest k (first-occurrence).
__global__ void vq_refine2(const float* __restrict__ zg, const float* __restrict__ emb,
                           const float* __restrict__ z2f, const float* __restrict__ e2f,
                           const int* __restrict__ list, const int* __restrict__ candcount,
                           const u32* __restrict__ candbuf, u64* __restrict__ refbuf) {
  const int w = threadIdx.x >> 6, lane = threadIdx.x & 63;
  int ccnt = *candcount; if (ccnt > CAND_CAP) ccnt = CAND_CAP;
  for (int i = blockIdx.x * 4 + w; i < ccnt; i += gridDim.x * 4) {
    const u32 rec = candbuf[i];
    const int p = (int)(rec >> 13), k = (int)(rec & 8191u);
    const int n = list[p] & (N_TOK - 1);
    float4 zv = ((const float4*)(zg + (size_t)n * D_DIM))[lane];
    float4 ev = ((const float4*)(emb + (size_t)k * D_DIM))[lane];
    double s = (double)zv.x * ev.x + (double)zv.y * ev.y +
               (double)zv.z * ev.z + (double)zv.w * ev.w;
    #pragma unroll
    for (int off = 32; off > 0; off >>= 1) s += __shfl_down(s, off);
    if (lane == 0) {
      float S = z2f[n] + e2f[k];           // fl32(z2+e2)
      float val = S - 2.0f * (float)s;     // fl32(S - 2*fl32(dot))
      u64 key = ((u64)__float_as_uint(val) << 13) | (u64)k;
      atomicMin((unsigned long long*)(refbuf + p), (unsigned long long)key);
    }
  }
}

// ---------------------------------------------------------------- gather
// f32 outputs: quantized = straight_through = emb[idx]; indices as f32.
__global__ void vq_gather(const float* __restrict__ emb, const int* __restrict__ idx1_ws,
                          const u64* __restrict__ refbuf, float* __restrict__ out) {
  const int w = threadIdx.x >> 6, lane = threadIdx.x & 63;
  const int n = blockIdx.x * 4 + w;
  const int enc = idx1_ws[n];
  int idx = enc & 8191;
  const int p = enc >> 13;
  if (p > 0) {
    u64 rb = refbuf[p - 1];
    if (rb != 0xFFFFFFFFFFFFFFFFULL) idx = (int)(rb & 8191ULL);
  }
  float4 v = ((const float4*)(emb + (size_t)idx * D_DIM))[lane];
  float4* o = (float4*)out;
  o[(size_t)n * 64 + lane] = v;
  o[(size_t)4194304 + (size_t)n * 64 + lane] = v;         // + N*D (float4 units)
  if (lane == 0) out[(size_t)33554432 + n] = (float)idx;  // + 2*N*D (float units)
}

extern "C" void kernel_launch(void* const* d_in, const int* in_sizes, int n_in,
                              void* d_out, int out_size, void* d_ws, size_t ws_size,
                              hipStream_t stream) {
  const float* z   = (const float*)d_in[0];
  const float* emb = (const float*)d_in[1];
  char* ws = (char*)d_ws;
  // Workspace layout (bytes), total 5,029,896 — within the 5.38 MB envelope.
  u16*   ehh       = (u16*)(ws);                  // [0        .. 4194304)
  float* e2f       = (float*)(ws + 4194304);      // [4194304  .. 4227072)
  u16*   e2h       = (u16*)(ws + 4227072);        // [4227072  .. 4243456)
  float* z2f       = (float*)(ws + 4243456);      // [4243456  .. 4505600)
  int*   idx1_ws   = (int*)(ws + 4505600);        // [4505600  .. 4767744)
  u64*   refbuf    = (u64*)(ws + 4767744);        // [4767744  .. 4866048)  12288*8
  int*   list      = (int*)(ws + 4866048);        // [4866048  .. 4915200)  12288*4
  int*   thrbuf    = (int*)(ws + 4915200);        // [4915200  .. 4964352)  12288*4
  u32*   candbuf   = (u32*)(ws + 4964352);        // [4964352  .. 5029888)  16384*4
  int*   count     = (int*)(ws + 5029888);        // [5029888  .. 5029892)
  int*   candcount = (int*)(ws + 5029892);        // [5029892  .. 5029896)

  vq_prep   <<<K_EMB / 4, 256, 0, stream>>>(emb, ehh, e2f, e2h, count, candcount);
  vq_phase1 <<<N_TOK / 256, 512, 0, stream>>>(z, ehh, e2h, z2f, idx1_ws, thrbuf,
                                              refbuf, list, count);
  vq_cand   <<<768, 512, 0, stream>>>(z, ehh, e2h, count, list, thrbuf,
                                      candbuf, candcount);
  vq_refine2<<<512, 256, 0, stream>>>(z, emb, z2f, e2f, list, candcount,
                                      candbuf, refbuf);
  vq_gather <<<N_TOK / 4, 256, 0, stream>>>(emb, idx1_ws, refbuf, (float*)d_out);
}